// Round 7
// baseline (184.944 us; speedup 1.0000x reference)
//
#include <hip/hip_runtime.h>
#include <hip/hip_bf16.h>
#include <stdint.h>

// QuantizedConv2d int8: x (32,128,56,56), w (256,128,3,3), pad 1, stride 1.
// Implicit GEMM on v_mfma_i32_32x32x32_i8. M=out-ch, N=pixels, K=9*128=1152.
// R16: FUSED x-packing. pack_x kernel + xp tensor deleted; each conv block
// gathers its 6 padded rows straight from x (NCHW int32), packs to int8 in
// registers, ds_write_b128 into lx with the same XOR swizzle involution the
// B-read uses (write cc -> slot cc^(pf&7); read slot cch^(pf&7)). Gathers are
// coalesced (consecutive lanes -> consecutive (h,w) raster). Saves the
// pack_x dispatch + xp HBM round-trip. Conv schedule = R12 (all seven
// schedule variants measured equal): per-tap weight dbuf, 1 barrier/tap,
// setprio on MFMA clusters, 79.4 KB LDS -> 2 blocks x 8 waves = 16 waves/CU.

#define NB   32
#define CIN  128
#define HO   56
#define WO   56
#define KOUT 256
#define HP   58

typedef int v4i  __attribute__((ext_vector_type(4)));
typedef int v16i __attribute__((ext_vector_type(16)));

static __device__ __forceinline__ void gload_lds16(const int8_t* g, int8_t* l) {
  __builtin_amdgcn_global_load_lds(
      (const __attribute__((address_space(1))) void*)g,
      (__attribute__((address_space(3))) void*)l, 16, 0, 0);
}

// ---- pack w: OIHW int32 -> [ktb(2)][tap(9)][cc(8)][ch(128)] 16B chunks ------
__global__ __launch_bounds__(256) void pack_w_kernel(const int* __restrict__ wgt,
                                                     int8_t* __restrict__ wq) {
  const int wid = blockIdx.x * 256 + threadIdx.x;   // 0..73727 int32 words
  const int wi = wid & 3;
  const int ci = wid >> 2;                          // chunk 0..18431
  const int ktb = ci / 9216;                        // 9216 = 9*8*128
  const int r  = ci - ktb * 9216;
  const int tap = r >> 10;                          // 1024 = 8*128
  const int r2  = r & 1023;
  const int cc  = r2 >> 7;
  const int ch  = r2 & 127;
  const int k_global = ktb * 128 + ch;
  const int cin0 = cc * 16 + wi * 4;
  const int base = (k_global * CIN + cin0) * 9 + tap;  // OIHW, 3x3=9 taps
  const int v0 = wgt[base];
  const int v1 = wgt[base + 9];
  const int v2 = wgt[base + 18];
  const int v3 = wgt[base + 27];
  reinterpret_cast<int*>(wq)[wid] =
      (v0 & 0xff) | ((v1 & 0xff) << 8) | ((v2 & 0xff) << 16) | (v3 << 24);
}

// -------- conv: fused x-gather staging + per-tap dbuf weights ---------------
// grid (14 rg, 32 n, 2 ktb) = 896 blocks, 512 threads = 8 waves.
// Block: 128 out-ch x 4 output rows. Wave (wr=row 0..3, wh=ch-half 0..1):
// 64 ch x 64 px, acc[2][2] = 64 VGPR. Per ks: 2 A + 2 B LDS b128 -> 4 MFMA.
__global__ __launch_bounds__(512, 4) void conv_kernel(const int* __restrict__ x,
                                                      const int8_t* __restrict__ wq,
                                                      const int* __restrict__ bias,
                                                      const float* __restrict__ wscale,
                                                      int* __restrict__ out) {
  __shared__ __align__(16) int8_t lw[2][8 * 128 * 16];        // 2 x 16,384 B
  __shared__ __align__(16) int8_t lx[(6 * HP + 8) * 8 * 16];  // 45,568 B (+pad)
  __shared__ int   bsh[128];
  __shared__ float ssh[128];

  const int tid = threadIdx.x;
  const int rg = blockIdx.x;           // row group 0..13
  const int n_img = blockIdx.y;
  const int ktb = blockIdx.z;          // 128-ch slice, slowest -> L2 reuse of x
  const int h0 = rg * 4;

  const int lane = tid & 63;
  const int wvi = tid >> 6;            // wave 0..7
  const int wr = wvi & 3;              // output row
  const int wh = wvi >> 2;             // 64-ch half
  const int p0 = lane & 31;
  const int half = lane >> 5;

  const int* x32 = x + (size_t)n_img * CIN * (HO * WO);  // this image, int32/elem
  const int8_t* wqt = wq + (size_t)ktb * (9 * 16384);

  // ---- fused stage: gather 6 padded rows from NCHW x, pack, swizzled write --
  // 2784 chunks; chunk i: cc = i/348 (k-chunk), pf = i%348 (= lr*58 + w).
  // Consecutive lanes -> consecutive pf -> consecutive (h,w) raster addrs.
  #pragma unroll
  for (int it = 0; it < 6; ++it) {
    const int i = it * 512 + tid;
    if (i < 2784) {
      const int cc = i / 348;
      const int pf = i - cc * 348;           // lr*58 + w
      const int lr = pf / 58;
      const int w  = pf - lr * 58;
      const int h  = h0 + lr - 1;            // padded row -> image row
      const int wp = w - 1;                  // padded col -> image col
      v4i v = {0, 0, 0, 0};
      if ((unsigned)h < (unsigned)HO && (unsigned)wp < (unsigned)WO) {
        const int* src = x32 + (cc * 16) * (HO * WO) + h * WO + wp;
        int b[16];
        #pragma unroll
        for (int q = 0; q < 16; ++q) b[q] = src[q * (HO * WO)];
        v[0] = (b[0] & 0xff) | ((b[1] & 0xff) << 8) | ((b[2] & 0xff) << 16) | (b[3] << 24);
        v[1] = (b[4] & 0xff) | ((b[5] & 0xff) << 8) | ((b[6] & 0xff) << 16) | (b[7] << 24);
        v[2] = (b[8] & 0xff) | ((b[9] & 0xff) << 8) | ((b[10] & 0xff) << 16) | (b[11] << 24);
        v[3] = (b[12] & 0xff) | ((b[13] & 0xff) << 8) | ((b[14] & 0xff) << 16) | (b[15] << 24);
      }
      // swizzled write: chunk cc of row pf -> slot cc^(pf&7)  (read inverts)
      *reinterpret_cast<v4i*>(lx + pf * CIN + ((cc ^ (pf & 7)) << 4)) = v;
    }
  }
  // ---- stage weights tap 0 ----
  gload_lds16(wqt + tid * 16,         lw[0] + tid * 16);
  gload_lds16(wqt + (512 + tid) * 16, lw[0] + (512 + tid) * 16);
  if (tid < 128) {
    const int ch = ktb * 128 + tid;
    bsh[tid] = bias[ch];
    ssh[tid] = (0.02f * wscale[ch]) / 0.05f;   // IN_SCALE * ws / OUT_SCALE
  }
  __syncthreads();

  v16i acc[2][2];                      // [mt: 32-ch tile][nt: 32-px tile]
  #pragma unroll
  for (int mt = 0; mt < 2; ++mt)
    #pragma unroll
    for (int nt = 0; nt < 2; ++nt)
      #pragma unroll
      for (int e = 0; e < 16; ++e) acc[mt][nt][e] = 0;

  const int chb = wh * 64;             // this wave's 64-ch half

  #pragma unroll
  for (int tap = 0; tap < 9; ++tap) {
    // prefetch next tap's weights into the other buffer (drained at barrier)
    if (tap < 8) {
      const int8_t* wsrc = wqt + (tap + 1) * 16384;
      int8_t* ldst = lw[(tap + 1) & 1];
      gload_lds16(wsrc + tid * 16,         ldst + tid * 16);
      gload_lds16(wsrc + (512 + tid) * 16, ldst + (512 + tid) * 16);
    }
    const int kh = (tap >= 3) + (tap >= 6);
    const int kw = tap - 3 * kh;
    const int8_t* lwt = lw[tap & 1];             // [cc(8)][ch(128)] chunk-major
    const int pfb = (wr + kh) * HP + kw;
    #pragma unroll
    for (int ks = 0; ks < 4; ++ks) {
      const int cch = 2 * ks + half;             // k-chunk for this lane
      const v4i a0 = *reinterpret_cast<const v4i*>(lwt + cch * 2048 + (chb + p0) * 16);
      const v4i a1 = *reinterpret_cast<const v4i*>(lwt + cch * 2048 + (chb + 32 + p0) * 16);
      const int pf0 = pfb + p0;
      const int pf1 = pfb + 32 + p0;
      const v4i b0 = *reinterpret_cast<const v4i*>(lx + pf0 * CIN + ((cch ^ (pf0 & 7)) << 4));
      const v4i b1 = *reinterpret_cast<const v4i*>(lx + pf1 * CIN + ((cch ^ (pf1 & 7)) << 4));
      // edge reads (pf>347) land in the lx pad; they feed only masked w>=56.
      __builtin_amdgcn_s_setprio(1);
      acc[0][0] = __builtin_amdgcn_mfma_i32_32x32x32_i8(a0, b0, acc[0][0], 0, 0, 0);
      acc[1][0] = __builtin_amdgcn_mfma_i32_32x32x32_i8(a1, b0, acc[1][0], 0, 0, 0);
      acc[0][1] = __builtin_amdgcn_mfma_i32_32x32x32_i8(a0, b1, acc[0][1], 0, 0, 0);
      acc[1][1] = __builtin_amdgcn_mfma_i32_32x32x32_i8(a1, b1, acc[1][1], 0, 0, 0);
      __builtin_amdgcn_s_setprio(0);
    }
    __syncthreads();                   // drains prefetch; guards dbuf swap
  }

  // ---- epilogue: D row = ch = mt*32 + (r&3)+8*(r>>2)+4*half, col = pixel ----
  const int h = h0 + wr;
  #pragma unroll
  for (int mt = 0; mt < 2; ++mt) {
    #pragma unroll
    for (int r = 0; r < 16; ++r) {
      const int cl = chb + mt * 32 + (r & 3) + 8 * (r >> 2) + 4 * half;
      const int bi = bsh[cl];
      const float sc = ssh[cl];
      int* ob = out + (((size_t)(n_img * KOUT + ktb * 128 + cl)) * HO + h) * WO;
      #pragma unroll
      for (int nt = 0; nt < 2; ++nt) {
        const int w = nt * 32 + p0;
        if (w < WO) {
          float v = (float)(acc[mt][nt][r] + bi) * sc;
          v = rintf(v);                          // round-half-even == jnp.round
          v = fminf(fmaxf(v, -128.0f), 127.0f);
          ob[w] = (int)v;
        }
      }
    }
  }
}

extern "C" void kernel_launch(void* const* d_in, const int* in_sizes, int n_in,
                              void* d_out, int out_size, void* d_ws, size_t ws_size,
                              hipStream_t stream) {
  const int* x = (const int*)d_in[0];
  const int* wgt = (const int*)d_in[1];
  const int* bias = (const int*)d_in[2];
  const float* wscale = (const float*)d_in[3];
  int* out = (int*)d_out;

  int8_t* wq = (int8_t*)d_ws;                               // 294,912 B only

  pack_w_kernel<<<288, 256, 0, stream>>>(wgt, wq);
  conv_kernel<<<dim3(14, 32, 2), 512, 0, stream>>>(x, wq, bias, wscale, out);
}